// Round 9
// baseline (381.078 us; speedup 1.0000x reference)
//
#include <hip/hip_runtime.h>

#define SEQ 79
#define DM 1024
#define BATCHN 512
#define NPB (SEQ * SEQ)             // 6241
#define P 36                        // k-pitch in floats (16B-aligned, odd/32 banks)
#define NST 395                     // 79 i * 5 j-subtiles of 16
#define NWAVES 16                   // 1024-thread block

typedef float v2f   __attribute__((ext_vector_type(2)));
typedef float f32x4 __attribute__((ext_vector_type(4)));
typedef short short8 __attribute__((ext_vector_type(8)));

__device__ __forceinline__ unsigned cvt_pk_bf16(float lo, float hi) {
    unsigned r;
    asm("v_cvt_pk_bf16_f32 %0, %1, %2" : "=v"(r) : "v"(lo), "v"(hi));
    return r;
}

__device__ __forceinline__ v2f gelu2(v2f a) {
    // gelu(a) = a - a / (exp2(c1*a + c2*a^3) + 1)
    const v2f C1 = {2.3022585093f, 2.3022585093f};
    const v2f C2 = {0.1029450750f, 0.1029450750f};
    v2f tt = a * (a * a * C2 + C1);
    v2f e;
    e.x = __builtin_amdgcn_exp2f(tt.x);
    e.y = __builtin_amdgcn_exp2f(tt.y);
    v2f ep = e + (v2f){1.f, 1.f};
    v2f r;
    r.x = __builtin_amdgcn_rcpf(ep.x);
    r.y = __builtin_amdgcn_rcpf(ep.y);
    return a - a * r;
}

// One 1024-thread block per batch (16 waves -> 32 waves/CU at 2 blocks/CU).
// Phase A: each wave computes token rows wv, wv+16, ... with a 1-row register
// prefetch; u'/v'/col written straight to LDS. Phase B: 16-pair subtiles,
// packed-f32 gelu, one mfma_f32_16x16x32_bf16 per subtile, coalesced stores.
__global__ __launch_bounds__(1024, 8) void fused_bias(
    const float* __restrict__ x,
    const float* __restrict__ piece_w, const float* __restrict__ piece_b,
    const float* __restrict__ color_w, const float* __restrict__ color_b,
    const float* __restrict__ mlp1_w,  const float* __restrict__ mlp1_b,
    const float* __restrict__ mlp2_w,  const float* __restrict__ mlp2_b,
    float* __restrict__ out)
{
    __shared__ float uL[80 * P];     // 11,520 B
    __shared__ float vL[80 * P];     // 11,520 B
    __shared__ float colL[80];       // row 79 never written; j==79 reads are
                                     // isolated to MFMA col 15 and discarded
    const int tid  = threadIdx.x;
    const int lane = tid & 63;
    const int wv   = tid >> 6;       // wave id 0..15
    const int b    = blockIdx.x;
    const int k    = lane & 31;
    const bool is_u = (lane < 32);

    // ---- phase-A per-lane projection weights: c = q*256 + lane*4 + t
    float wp[4][4][7];
#pragma unroll
    for (int q = 0; q < 4; ++q)
#pragma unroll
        for (int t = 0; t < 4; ++t) {
            const int c = q * 256 + lane * 4 + t;
#pragma unroll
            for (int e = 0; e < 6; ++e) wp[q][t][e] = piece_w[c * 6 + e];
            wp[q][t][6] = color_w[c];
        }

    float wsp0 = mlp1_w[0 * 32 + k];
    float wsp1 = mlp1_w[1 * 32 + k];
    if (!is_u) { wsp0 = -wsp0; wsp1 = -wsp1; }
    const float bias1 = is_u ? mlp1_b[k] : 0.0f;
    float wc[6];
#pragma unroll
    for (int c = 0; c < 6; ++c)
        wc[c] = mlp1_w[((is_u ? 2 : 8) + c) * 32 + k];
    float pb[6];
#pragma unroll
    for (int e = 0; e < 6; ++e) pb[e] = piece_b[e];
    const float cb = color_b[0];

    // ---- phase-B lane constants
    const int e16 = lane & 15;          // j-in-subtile / W2 output index
    const int kq  = lane >> 4;          // k-quarter
    const int k0  = kq * 8;

    union { unsigned w[4]; short8 s; } A;   // A-frag = W2^T (rows 8..15 zero)
#pragma unroll
    for (int w = 0; w < 4; ++w) {
        const float lo = (e16 < 8) ? mlp2_w[(k0 + 2 * w) * 8 + e16] : 0.0f;
        const float hi = (e16 < 8) ? mlp2_w[(k0 + 2 * w + 1) * 8 + e16] : 0.0f;
        A.w[w] = cvt_pk_bf16(lo, hi);
    }
    v2f w14p[4];
#pragma unroll
    for (int w = 0; w < 4; ++w)
        w14p[w] = (v2f){mlp1_w[14 * 32 + k0 + 2 * w], mlp1_w[14 * 32 + k0 + 2 * w + 1]};
    float b2v[4];
#pragma unroll
    for (int q = 0; q < 4; ++q)
        b2v[q] = (kq < 2) ? mlp2_b[kq * 4 + q] : 0.0f;

    // ---------------- Phase A: 79 token rows -> LDS ----------------
    const float* xb = x + (size_t)b * SEQ * DM;
    float4 xv[4];
    if (wv < SEQ) {
        const float4* xr = (const float4*)(xb + (size_t)wv * DM);
#pragma unroll
        for (int q = 0; q < 4; ++q) xv[q] = xr[q * 64 + lane];
    }
    for (int n = wv; n < SEQ; n += NWAVES) {
        // prefetch next row before the long reduce chain
        const int n2 = n + NWAVES;
        float4 xn[4];
        if (n2 < SEQ) {
            const float4* xr2 = (const float4*)(xb + (size_t)n2 * DM);
#pragma unroll
            for (int q = 0; q < 4; ++q) xn[q] = xr2[q * 64 + lane];
        }

        float acc[7] = {0.f, 0.f, 0.f, 0.f, 0.f, 0.f, 0.f};
#pragma unroll
        for (int q = 0; q < 4; ++q) {
            const float xs[4] = {xv[q].x, xv[q].y, xv[q].z, xv[q].w};
#pragma unroll
            for (int t = 0; t < 4; ++t)
#pragma unroll
                for (int e = 0; e < 7; ++e)
                    acc[e] = fmaf(xs[t], wp[q][t][e], acc[e]);
        }

#pragma unroll
        for (int e = 0; e < 7; ++e) {
#pragma unroll
            for (int m = 32; m >= 1; m >>= 1)
                acc[e] += __shfl_xor(acc[e], m, 64);
        }

        float p[6];
#pragma unroll
        for (int e = 0; e < 6; ++e) p[e] = acc[e] + pb[e];

        const float fx = (n < 64) ? (float)(n >> 3) : 0.0f;
        const float fy = (n < 64) ? (float)(n & 7) : 0.0f;

        float val = bias1;
        val = fmaf(fx, wsp0, val);
        val = fmaf(fy, wsp1, val);
#pragma unroll
        for (int c = 0; c < 6; ++c) val = fmaf(p[c], wc[c], val);

        float* dst = is_u ? uL : vL;
        dst[n * P + k] = val;
        if (lane == 0) colL[n] = acc[6] + cb;

#pragma unroll
        for (int q = 0; q < 4; ++q) xv[q] = xn[q];
    }

    __syncthreads();

    // ---------------- Phase B: 395 subtiles of 16 pairs ----------------
    const size_t obb = (size_t)b * (8 * NPB);
    for (int st = wv; st < NST; st += NWAVES) {
        const int i  = st / 5;             // wave-uniform
        const int jt = st - 5 * i;
        const int j  = jt * 16 + e16;      // 79 possible on last subtile

        const float4 ua = *(const float4*)(uL + i * P + k0);   // broadcast
        const float4 ub = *(const float4*)(uL + i * P + k0 + 4);
        const float ci = colL[i];
        const float4 va = *(const float4*)(vL + j * P + k0);   // stride-1
        const float4 vb = *(const float4*)(vL + j * P + k0 + 4);
        const float sw = (ci == colL[j]) ? 1.0f : 0.0f;
        const v2f swp = {sw, sw};

        const float uu[8] = {ua.x, ua.y, ua.z, ua.w, ub.x, ub.y, ub.z, ub.w};
        const float vv[8] = {va.x, va.y, va.z, va.w, vb.x, vb.y, vb.z, vb.w};

        union { unsigned w[4]; short8 s; } B;
#pragma unroll
        for (int w = 0; w < 4; ++w) {
            v2f a = {uu[2 * w] + vv[2 * w], uu[2 * w + 1] + vv[2 * w + 1]};
            a = a + swp * w14p[w];
            const v2f h = gelu2(a);
            B.w[w] = cvt_pk_bf16(h.x, h.y);
        }

        f32x4 acc2 = {0.f, 0.f, 0.f, 0.f};
        acc2 = __builtin_amdgcn_mfma_f32_16x16x32_bf16(A.s, B.s, acc2, 0, 0, 0);

        // D: col = e16 (j), row = kq*4+q (e); rows 0..7 valid
        if (kq < 2 && j < SEQ) {
            float* o = out + obb + (size_t)(kq * 4) * NPB + (size_t)i * SEQ + j;
#pragma unroll
            for (int q = 0; q < 4; ++q)
                o[(size_t)q * NPB] = acc2[q] + b2v[q];
        }
    }
}

extern "C" void kernel_launch(void* const* d_in, const int* in_sizes, int n_in,
                              void* d_out, int out_size, void* d_ws, size_t ws_size,
                              hipStream_t stream) {
    const float* x       = (const float*)d_in[0];
    const float* piece_w = (const float*)d_in[1];
    const float* piece_b = (const float*)d_in[2];
    const float* color_w = (const float*)d_in[3];
    const float* color_b = (const float*)d_in[4];
    const float* mlp1_w  = (const float*)d_in[5];
    const float* mlp1_b  = (const float*)d_in[6];
    const float* mlp2_w  = (const float*)d_in[7];
    const float* mlp2_b  = (const float*)d_in[8];
    float* out = (float*)d_out;

    hipLaunchKernelGGL(fused_bias, dim3(BATCHN), dim3(1024), 0, stream,
                       x, piece_w, piece_b, color_w, color_b,
                       mlp1_w, mlp1_b, mlp2_w, mlp2_b, out);
}

// Round 10
// 139.077 us; speedup vs baseline: 2.7401x; 2.7401x over previous
//
#include <hip/hip_runtime.h>

#define SEQ 79
#define DM 1024
#define BATCHN 512
#define NPB (SEQ * SEQ)             // 6241
#define P 36                        // k-pitch in floats (16B-aligned, odd/32 banks)
#define NST 395                     // 79 i * 5 j-subtiles of 16
#define NWAVES 8                    // 512-thread block

typedef float v2f   __attribute__((ext_vector_type(2)));
typedef float f32x4 __attribute__((ext_vector_type(4)));
typedef short short8 __attribute__((ext_vector_type(8)));

__device__ __forceinline__ unsigned cvt_pk_bf16(float lo, float hi) {
    unsigned r;
    asm("v_cvt_pk_bf16_f32 %0, %1, %2" : "=v"(r) : "v"(lo), "v"(hi));
    return r;
}

__device__ __forceinline__ v2f gelu2(v2f a) {
    // gelu(a) = a - a / (exp2(c1*a + c2*a^3) + 1)
    const v2f C1 = {2.3022585093f, 2.3022585093f};
    const v2f C2 = {0.1029450750f, 0.1029450750f};
    v2f tt = a * (a * a * C2 + C1);
    v2f e;
    e.x = __builtin_amdgcn_exp2f(tt.x);
    e.y = __builtin_amdgcn_exp2f(tt.y);
    v2f ep = e + (v2f){1.f, 1.f};
    v2f r;
    r.x = __builtin_amdgcn_rcpf(ep.x);
    r.y = __builtin_amdgcn_rcpf(ep.y);
    return a - a * r;
}

// One 512-thread block per batch (8 waves; 2 blocks/CU -> 16 waves/CU).
// __launch_bounds__(512,4): VGPR cap 128 > the 88 this body needs -> NO spill
// (R9's (1024,8) capped at 32 VGPR and spilled wp[] to scratch: 826 MB fetch).
// Phase A: each wave computes token rows wv, wv+8, ...; u'/v'/col -> LDS.
// Phase B: 16-pair subtiles, packed-f32 gelu, one mfma per subtile.
__global__ __launch_bounds__(512, 4) void fused_bias(
    const float* __restrict__ x,
    const float* __restrict__ piece_w, const float* __restrict__ piece_b,
    const float* __restrict__ color_w, const float* __restrict__ color_b,
    const float* __restrict__ mlp1_w,  const float* __restrict__ mlp1_b,
    const float* __restrict__ mlp2_w,  const float* __restrict__ mlp2_b,
    float* __restrict__ out)
{
    __shared__ float uL[80 * P];     // 11,520 B
    __shared__ float vL[80 * P];     // 11,520 B
    __shared__ float colL[80];       // row 79 never written; j==79 reads are
                                     // isolated to MFMA col 15 and discarded
    const int tid  = threadIdx.x;
    const int lane = tid & 63;
    const int wv   = tid >> 6;       // wave id 0..7
    const int b    = blockIdx.x;
    const int k    = lane & 31;
    const bool is_u = (lane < 32);

    // ---- phase-A per-lane projection weights: c = q*256 + lane*4 + t
    float wp[4][4][7];
#pragma unroll
    for (int q = 0; q < 4; ++q)
#pragma unroll
        for (int t = 0; t < 4; ++t) {
            const int c = q * 256 + lane * 4 + t;
#pragma unroll
            for (int e = 0; e < 6; ++e) wp[q][t][e] = piece_w[c * 6 + e];
            wp[q][t][6] = color_w[c];
        }

    float wsp0 = mlp1_w[0 * 32 + k];
    float wsp1 = mlp1_w[1 * 32 + k];
    if (!is_u) { wsp0 = -wsp0; wsp1 = -wsp1; }
    const float bias1 = is_u ? mlp1_b[k] : 0.0f;
    float wc[6];
#pragma unroll
    for (int c = 0; c < 6; ++c)
        wc[c] = mlp1_w[((is_u ? 2 : 8) + c) * 32 + k];
    float pb[6];
#pragma unroll
    for (int e = 0; e < 6; ++e) pb[e] = piece_b[e];
    const float cb = color_b[0];

    // ---- phase-B lane constants
    const int e16 = lane & 15;          // j-in-subtile / W2 output index
    const int kq  = lane >> 4;          // k-quarter
    const int k0  = kq * 8;

    union { unsigned w[4]; short8 s; } A;   // A-frag = W2^T (rows 8..15 zero)
#pragma unroll
    for (int w = 0; w < 4; ++w) {
        const float lo = (e16 < 8) ? mlp2_w[(k0 + 2 * w) * 8 + e16] : 0.0f;
        const float hi = (e16 < 8) ? mlp2_w[(k0 + 2 * w + 1) * 8 + e16] : 0.0f;
        A.w[w] = cvt_pk_bf16(lo, hi);
    }
    v2f w14p[4];
#pragma unroll
    for (int w = 0; w < 4; ++w)
        w14p[w] = (v2f){mlp1_w[14 * 32 + k0 + 2 * w], mlp1_w[14 * 32 + k0 + 2 * w + 1]};
    float b2v[4];
#pragma unroll
    for (int q = 0; q < 4; ++q)
        b2v[q] = (kq < 2) ? mlp2_b[kq * 4 + q] : 0.0f;

    // ---------------- Phase A: 79 token rows -> LDS ----------------
    const float* xb = x + (size_t)b * SEQ * DM;
    for (int n = wv; n < SEQ; n += NWAVES) {
        const float4* xr = (const float4*)(xb + (size_t)n * DM);
        float4 xv[4];
#pragma unroll
        for (int q = 0; q < 4; ++q) xv[q] = xr[q * 64 + lane];

        float acc[7] = {0.f, 0.f, 0.f, 0.f, 0.f, 0.f, 0.f};
#pragma unroll
        for (int q = 0; q < 4; ++q) {
            const float xs[4] = {xv[q].x, xv[q].y, xv[q].z, xv[q].w};
#pragma unroll
            for (int t = 0; t < 4; ++t)
#pragma unroll
                for (int e = 0; e < 7; ++e)
                    acc[e] = fmaf(xs[t], wp[q][t][e], acc[e]);
        }

#pragma unroll
        for (int e = 0; e < 7; ++e) {
#pragma unroll
            for (int m = 32; m >= 1; m >>= 1)
                acc[e] += __shfl_xor(acc[e], m, 64);
        }

        float p[6];
#pragma unroll
        for (int e = 0; e < 6; ++e) p[e] = acc[e] + pb[e];

        const float fx = (n < 64) ? (float)(n >> 3) : 0.0f;
        const float fy = (n < 64) ? (float)(n & 7) : 0.0f;

        float val = bias1;
        val = fmaf(fx, wsp0, val);
        val = fmaf(fy, wsp1, val);
#pragma unroll
        for (int c = 0; c < 6; ++c) val = fmaf(p[c], wc[c], val);

        float* dst = is_u ? uL : vL;
        dst[n * P + k] = val;
        if (lane == 0) colL[n] = acc[6] + cb;
    }

    __syncthreads();

    // ---------------- Phase B: 395 subtiles of 16 pairs ----------------
    const size_t obb = (size_t)b * (8 * NPB);
    for (int st = wv; st < NST; st += NWAVES) {
        const int i  = st / 5;             // wave-uniform
        const int jt = st - 5 * i;
        const int j  = jt * 16 + e16;      // 79 possible on last subtile

        const float4 ua = *(const float4*)(uL + i * P + k0);   // broadcast
        const float4 ub = *(const float4*)(uL + i * P + k0 + 4);
        const float ci = colL[i];
        const float4 va = *(const float4*)(vL + j * P + k0);   // stride-1
        const float4 vb = *(const float4*)(vL + j * P + k0 + 4);
        const float sw = (ci == colL[j]) ? 1.0f : 0.0f;
        const v2f swp = {sw, sw};

        const float uu[8] = {ua.x, ua.y, ua.z, ua.w, ub.x, ub.y, ub.z, ub.w};
        const float vv[8] = {va.x, va.y, va.z, va.w, vb.x, vb.y, vb.z, vb.w};

        union { unsigned w[4]; short8 s; } B;
#pragma unroll
        for (int w = 0; w < 4; ++w) {
            v2f a = {uu[2 * w] + vv[2 * w], uu[2 * w + 1] + vv[2 * w + 1]};
            a = a + swp * w14p[w];
            const v2f h = gelu2(a);
            B.w[w] = cvt_pk_bf16(h.x, h.y);
        }

        f32x4 acc2 = {0.f, 0.f, 0.f, 0.f};
        acc2 = __builtin_amdgcn_mfma_f32_16x16x32_bf16(A.s, B.s, acc2, 0, 0, 0);

        // D: col = e16 (j), row = kq*4+q (e); rows 0..7 valid
        if (kq < 2 && j < SEQ) {
            float* o = out + obb + (size_t)(kq * 4) * NPB + (size_t)i * SEQ + j;
#pragma unroll
            for (int q = 0; q < 4; ++q)
                o[(size_t)q * NPB] = acc2[q] + b2v[q];
        }
    }
}

extern "C" void kernel_launch(void* const* d_in, const int* in_sizes, int n_in,
                              void* d_out, int out_size, void* d_ws, size_t ws_size,
                              hipStream_t stream) {
    const float* x       = (const float*)d_in[0];
    const float* piece_w = (const float*)d_in[1];
    const float* piece_b = (const float*)d_in[2];
    const float* color_w = (const float*)d_in[3];
    const float* color_b = (const float*)d_in[4];
    const float* mlp1_w  = (const float*)d_in[5];
    const float* mlp1_b  = (const float*)d_in[6];
    const float* mlp2_w  = (const float*)d_in[7];
    const float* mlp2_b  = (const float*)d_in[8];
    float* out = (float*)d_out;

    hipLaunchKernelGGL(fused_bias, dim3(BATCHN), dim3(512), 0, stream,
                       x, piece_w, piece_b, color_w, color_b,
                       mlp1_w, mlp1_b, mlp2_w, mlp2_b, out);
}

// Round 11
// 103.831 us; speedup vs baseline: 3.6702x; 1.3395x over previous
//
#include <hip/hip_runtime.h>

#define SEQ 79
#define DM 1024
#define BATCHN 512
#define NPB (SEQ * SEQ)             // 6241
#define P 36                        // k-pitch in floats (16B-aligned, odd/32 banks)
#define NST 395                     // 79 i * 5 j-subtiles of 16
#define NWAVES 4                    // 256-thread block
#define HALF0 198                   // subtile split point between the 2 blocks/batch

typedef float v2f   __attribute__((ext_vector_type(2)));
typedef float f32x4 __attribute__((ext_vector_type(4)));
typedef short short8 __attribute__((ext_vector_type(8)));

__device__ __forceinline__ unsigned cvt_pk_bf16(float lo, float hi) {
    unsigned r;
    asm("v_cvt_pk_bf16_f32 %0, %1, %2" : "=v"(r) : "v"(lo), "v"(hi));
    return r;
}

__device__ __forceinline__ v2f gelu2(v2f a) {
    // gelu(a) = a - a / (exp2(c1*a + c2*a^3) + 1)
    const v2f C1 = {2.3022585093f, 2.3022585093f};
    const v2f C2 = {0.1029450750f, 0.1029450750f};
    v2f tt = a * (a * a * C2 + C1);
    v2f e;
    e.x = __builtin_amdgcn_exp2f(tt.x);
    e.y = __builtin_amdgcn_exp2f(tt.y);
    v2f ep = e + (v2f){1.f, 1.f};
    v2f r;
    r.x = __builtin_amdgcn_rcpf(ep.x);
    r.y = __builtin_amdgcn_rcpf(ep.y);
    return a - a * r;
}

// Two 256-thread blocks per batch (grid 1024 -> 4 blocks/CU, 16 waves/CU).
// Each block runs the FULL phase A (cheap: x is L3-resident, compute ~7us
// device-wide even duplicated) into its own LDS, then HALF of phase B.
// __launch_bounds__(256,2) = the R8-proven codegen: 88 VGPR, no spill.
// (R9 (1024,8)->32 VGPR and R10 (512,4)->64 VGPR both spilled wp[]: +70-150MB
// scratch traffic. Do not press the register allocator below ~88.)
__global__ __launch_bounds__(256, 2) void fused_bias(
    const float* __restrict__ x,
    const float* __restrict__ piece_w, const float* __restrict__ piece_b,
    const float* __restrict__ color_w, const float* __restrict__ color_b,
    const float* __restrict__ mlp1_w,  const float* __restrict__ mlp1_b,
    const float* __restrict__ mlp2_w,  const float* __restrict__ mlp2_b,
    float* __restrict__ out)
{
    __shared__ float uL[80 * P];     // 11,520 B
    __shared__ float vL[80 * P];     // 11,520 B
    __shared__ float colL[80];       // row 79 never written; j==79 reads are
                                     // isolated to MFMA col 15 and discarded
    const int tid  = threadIdx.x;
    const int lane = tid & 63;
    const int wv   = tid >> 6;       // wave id 0..3
    const int b    = blockIdx.x >> 1;
    const int half = blockIdx.x & 1;
    const int k    = lane & 31;
    const bool is_u = (lane < 32);

    // ---- phase-A per-lane projection weights: c = q*256 + lane*4 + t
    float wp[4][4][7];
#pragma unroll
    for (int q = 0; q < 4; ++q)
#pragma unroll
        for (int t = 0; t < 4; ++t) {
            const int c = q * 256 + lane * 4 + t;
#pragma unroll
            for (int e = 0; e < 6; ++e) wp[q][t][e] = piece_w[c * 6 + e];
            wp[q][t][6] = color_w[c];
        }

    float wsp0 = mlp1_w[0 * 32 + k];
    float wsp1 = mlp1_w[1 * 32 + k];
    if (!is_u) { wsp0 = -wsp0; wsp1 = -wsp1; }
    const float bias1 = is_u ? mlp1_b[k] : 0.0f;
    float wc[6];
#pragma unroll
    for (int c = 0; c < 6; ++c)
        wc[c] = mlp1_w[((is_u ? 2 : 8) + c) * 32 + k];
    float pb[6];
#pragma unroll
    for (int e = 0; e < 6; ++e) pb[e] = piece_b[e];
    const float cb = color_b[0];

    // ---- phase-B lane constants
    const int e16 = lane & 15;          // j-in-subtile / W2 output index
    const int kq  = lane >> 4;          // k-quarter
    const int k0  = kq * 8;

    union { unsigned w[4]; short8 s; } A;   // A-frag = W2^T (rows 8..15 zero)
#pragma unroll
    for (int w = 0; w < 4; ++w) {
        const float lo = (e16 < 8) ? mlp2_w[(k0 + 2 * w) * 8 + e16] : 0.0f;
        const float hi = (e16 < 8) ? mlp2_w[(k0 + 2 * w + 1) * 8 + e16] : 0.0f;
        A.w[w] = cvt_pk_bf16(lo, hi);
    }
    v2f w14p[4];
#pragma unroll
    for (int w = 0; w < 4; ++w)
        w14p[w] = (v2f){mlp1_w[14 * 32 + k0 + 2 * w], mlp1_w[14 * 32 + k0 + 2 * w + 1]};
    float b2v[4];
#pragma unroll
    for (int q = 0; q < 4; ++q)
        b2v[q] = (kq < 2) ? mlp2_b[kq * 4 + q] : 0.0f;

    // ---------------- Phase A: 79 token rows -> LDS ----------------
    const float* xb = x + (size_t)b * SEQ * DM;
    for (int n = wv; n < SEQ; n += NWAVES) {
        const float4* xr = (const float4*)(xb + (size_t)n * DM);
        float4 xv[4];
#pragma unroll
        for (int q = 0; q < 4; ++q) xv[q] = xr[q * 64 + lane];

        float acc[7] = {0.f, 0.f, 0.f, 0.f, 0.f, 0.f, 0.f};
#pragma unroll
        for (int q = 0; q < 4; ++q) {
            const float xs[4] = {xv[q].x, xv[q].y, xv[q].z, xv[q].w};
#pragma unroll
            for (int t = 0; t < 4; ++t)
#pragma unroll
                for (int e = 0; e < 7; ++e)
                    acc[e] = fmaf(xs[t], wp[q][t][e], acc[e]);
        }

#pragma unroll
        for (int e = 0; e < 7; ++e) {
#pragma unroll
            for (int m = 32; m >= 1; m >>= 1)
                acc[e] += __shfl_xor(acc[e], m, 64);
        }

        float p[6];
#pragma unroll
        for (int e = 0; e < 6; ++e) p[e] = acc[e] + pb[e];

        const float fx = (n < 64) ? (float)(n >> 3) : 0.0f;
        const float fy = (n < 64) ? (float)(n & 7) : 0.0f;

        float val = bias1;
        val = fmaf(fx, wsp0, val);
        val = fmaf(fy, wsp1, val);
#pragma unroll
        for (int c = 0; c < 6; ++c) val = fmaf(p[c], wc[c], val);

        float* dst = is_u ? uL : vL;
        dst[n * P + k] = val;
        if (lane == 0) colL[n] = acc[6] + cb;
    }

    __syncthreads();

    // ---------------- Phase B: this block's half of 395 subtiles ----------
    const int stlo = half ? HALF0 : 0;
    const int sthi = half ? NST : HALF0;
    const size_t obb = (size_t)b * (8 * NPB);
    for (int st = stlo + wv; st < sthi; st += NWAVES) {
        const int i  = st / 5;             // wave-uniform
        const int jt = st - 5 * i;
        const int j  = jt * 16 + e16;      // 79 possible on last subtile

        const float4 ua = *(const float4*)(uL + i * P + k0);   // broadcast
        const float4 ub = *(const float4*)(uL + i * P + k0 + 4);
        const float ci = colL[i];
        const float4 va = *(const float4*)(vL + j * P + k0);   // stride-1
        const float4 vb = *(const float4*)(vL + j * P + k0 + 4);
        const float sw = (ci == colL[j]) ? 1.0f : 0.0f;
        const v2f swp = {sw, sw};

        const float uu[8] = {ua.x, ua.y, ua.z, ua.w, ub.x, ub.y, ub.z, ub.w};
        const float vv[8] = {va.x, va.y, va.z, va.w, vb.x, vb.y, vb.z, vb.w};

        union { unsigned w[4]; short8 s; } B;
#pragma unroll
        for (int w = 0; w < 4; ++w) {
            v2f a = {uu[2 * w] + vv[2 * w], uu[2 * w + 1] + vv[2 * w + 1]};
            a = a + swp * w14p[w];
            const v2f h = gelu2(a);
            B.w[w] = cvt_pk_bf16(h.x, h.y);
        }

        f32x4 acc2 = {0.f, 0.f, 0.f, 0.f};
        acc2 = __builtin_amdgcn_mfma_f32_16x16x32_bf16(A.s, B.s, acc2, 0, 0, 0);

        // D: col = e16 (j), row = kq*4+q (e); rows 0..7 valid
        if (kq < 2 && j < SEQ) {
            float* o = out + obb + (size_t)(kq * 4) * NPB + (size_t)i * SEQ + j;
#pragma unroll
            for (int q = 0; q < 4; ++q)
                o[(size_t)q * NPB] = acc2[q] + b2v[q];
        }
    }
}

extern "C" void kernel_launch(void* const* d_in, const int* in_sizes, int n_in,
                              void* d_out, int out_size, void* d_ws, size_t ws_size,
                              hipStream_t stream) {
    const float* x       = (const float*)d_in[0];
    const float* piece_w = (const float*)d_in[1];
    const float* piece_b = (const float*)d_in[2];
    const float* color_w = (const float*)d_in[3];
    const float* color_b = (const float*)d_in[4];
    const float* mlp1_w  = (const float*)d_in[5];
    const float* mlp1_b  = (const float*)d_in[6];
    const float* mlp2_w  = (const float*)d_in[7];
    const float* mlp2_b  = (const float*)d_in[8];
    float* out = (float*)d_out;

    hipLaunchKernelGGL(fused_bias, dim3(BATCHN * 2), dim3(256), 0, stream,
                       x, piece_w, piece_b, color_w, color_b,
                       mlp1_w, mlp1_b, mlp2_w, mlp2_b, out);
}

// Round 12
// 89.029 us; speedup vs baseline: 4.2804x; 1.1663x over previous
//
#include <hip/hip_runtime.h>

#define SEQ 79
#define DM 1024
#define BATCHN 512
#define NPB (SEQ * SEQ)             // 6241
#define P 36                        // k-pitch in floats (16B-aligned, odd/32 banks)
#define NST 395                     // 79 i * 5 j-subtiles of 16
#define NWAVES 8                    // 512-thread block

typedef float v2f   __attribute__((ext_vector_type(2)));
typedef float f32x4 __attribute__((ext_vector_type(4)));
typedef short short8 __attribute__((ext_vector_type(8)));

__device__ __forceinline__ unsigned cvt_pk_bf16(float lo, float hi) {
    unsigned r;
    asm("v_cvt_pk_bf16_f32 %0, %1, %2" : "=v"(r) : "v"(lo), "v"(hi));
    return r;
}

__device__ __forceinline__ v2f gelu2(v2f a) {
    // gelu(a) = a - a / (exp2(c1*a + c2*a^3) + 1)
    const v2f C1 = {2.3022585093f, 2.3022585093f};
    const v2f C2 = {0.1029450750f, 0.1029450750f};
    v2f tt = a * (a * a * C2 + C1);
    v2f e;
    e.x = __builtin_amdgcn_exp2f(tt.x);
    e.y = __builtin_amdgcn_exp2f(tt.y);
    v2f ep = e + (v2f){1.f, 1.f};
    v2f r;
    r.x = __builtin_amdgcn_rcpf(ep.x);
    r.y = __builtin_amdgcn_rcpf(ep.y);
    return a - a * r;
}

// One 512-thread block per batch (8 waves). LDS 23.5KB -> 2 blocks/CU
// resident = 16 waves/CU, the HW ceiling for an ~88-VGPR body (waves halve
// at 64/128/256 VGPR).
// VGPR-cap empirical rule on this compiler: cap = 256/launch_bounds_arg2.
//   R9 (1024,8)->32 spill; R10 (512,4)->64 spill; R8 (256,2)->88 clean.
// (512,2) -> cap 128 >= 88 -> the proven codegen at 2x the waves/block.
// TRIPWIRE: if VGPR_Count <= 64 this failed -> revert to (256,2).
__global__ __launch_bounds__(512, 2) void fused_bias(
    const float* __restrict__ x,
    const float* __restrict__ piece_w, const float* __restrict__ piece_b,
    const float* __restrict__ color_w, const float* __restrict__ color_b,
    const float* __restrict__ mlp1_w,  const float* __restrict__ mlp1_b,
    const float* __restrict__ mlp2_w,  const float* __restrict__ mlp2_b,
    float* __restrict__ out)
{
    __shared__ float uL[80 * P];     // 11,520 B
    __shared__ float vL[80 * P];     // 11,520 B
    __shared__ float colL[80];       // row 79 never written; j==79 reads are
                                     // isolated to MFMA col 15 and discarded
    const int tid  = threadIdx.x;
    const int lane = tid & 63;
    const int wv   = tid >> 6;       // wave id 0..7
    const int b    = blockIdx.x;
    const int k    = lane & 31;
    const bool is_u = (lane < 32);

    // ---- phase-A per-lane projection weights: c = q*256 + lane*4 + t
    float wp[4][4][7];
#pragma unroll
    for (int q = 0; q < 4; ++q)
#pragma unroll
        for (int t = 0; t < 4; ++t) {
            const int c = q * 256 + lane * 4 + t;
#pragma unroll
            for (int e = 0; e < 6; ++e) wp[q][t][e] = piece_w[c * 6 + e];
            wp[q][t][6] = color_w[c];
        }

    float wsp0 = mlp1_w[0 * 32 + k];
    float wsp1 = mlp1_w[1 * 32 + k];
    if (!is_u) { wsp0 = -wsp0; wsp1 = -wsp1; }
    const float bias1 = is_u ? mlp1_b[k] : 0.0f;
    float wc[6];
#pragma unroll
    for (int c = 0; c < 6; ++c)
        wc[c] = mlp1_w[((is_u ? 2 : 8) + c) * 32 + k];
    float pb[6];
#pragma unroll
    for (int e = 0; e < 6; ++e) pb[e] = piece_b[e];
    const float cb = color_b[0];

    // ---- phase-B lane constants
    const int e16 = lane & 15;          // j-in-subtile / W2 output index
    const int kq  = lane >> 4;          // k-quarter
    const int k0  = kq * 8;

    union { unsigned w[4]; short8 s; } A;   // A-frag = W2^T (rows 8..15 zero)
#pragma unroll
    for (int w = 0; w < 4; ++w) {
        const float lo = (e16 < 8) ? mlp2_w[(k0 + 2 * w) * 8 + e16] : 0.0f;
        const float hi = (e16 < 8) ? mlp2_w[(k0 + 2 * w + 1) * 8 + e16] : 0.0f;
        A.w[w] = cvt_pk_bf16(lo, hi);
    }
    v2f w14p[4];
#pragma unroll
    for (int w = 0; w < 4; ++w)
        w14p[w] = (v2f){mlp1_w[14 * 32 + k0 + 2 * w], mlp1_w[14 * 32 + k0 + 2 * w + 1]};
    float b2v[4];
#pragma unroll
    for (int q = 0; q < 4; ++q)
        b2v[q] = (kq < 2) ? mlp2_b[kq * 4 + q] : 0.0f;

    // ---------------- Phase A: 79 token rows -> LDS ----------------
    const float* xb = x + (size_t)b * SEQ * DM;
    for (int n = wv; n < SEQ; n += NWAVES) {
        const float4* xr = (const float4*)(xb + (size_t)n * DM);
        float4 xv[4];
#pragma unroll
        for (int q = 0; q < 4; ++q) xv[q] = xr[q * 64 + lane];

        float acc[7] = {0.f, 0.f, 0.f, 0.f, 0.f, 0.f, 0.f};
#pragma unroll
        for (int q = 0; q < 4; ++q) {
            const float xs[4] = {xv[q].x, xv[q].y, xv[q].z, xv[q].w};
#pragma unroll
            for (int t = 0; t < 4; ++t)
#pragma unroll
                for (int e = 0; e < 7; ++e)
                    acc[e] = fmaf(xs[t], wp[q][t][e], acc[e]);
        }

#pragma unroll
        for (int e = 0; e < 7; ++e) {
#pragma unroll
            for (int m = 32; m >= 1; m >>= 1)
                acc[e] += __shfl_xor(acc[e], m, 64);
        }

        float p[6];
#pragma unroll
        for (int e = 0; e < 6; ++e) p[e] = acc[e] + pb[e];

        const float fx = (n < 64) ? (float)(n >> 3) : 0.0f;
        const float fy = (n < 64) ? (float)(n & 7) : 0.0f;

        float val = bias1;
        val = fmaf(fx, wsp0, val);
        val = fmaf(fy, wsp1, val);
#pragma unroll
        for (int c = 0; c < 6; ++c) val = fmaf(p[c], wc[c], val);

        float* dst = is_u ? uL : vL;
        dst[n * P + k] = val;
        if (lane == 0) colL[n] = acc[6] + cb;
    }

    __syncthreads();

    // ---------------- Phase B: 395 subtiles of 16 pairs ----------------
    const size_t obb = (size_t)b * (8 * NPB);
    for (int st = wv; st < NST; st += NWAVES) {
        const int i  = st / 5;             // wave-uniform
        const int jt = st - 5 * i;
        const int j  = jt * 16 + e16;      // 79 possible on last subtile

        const float4 ua = *(const float4*)(uL + i * P + k0);   // broadcast
        const float4 ub = *(const float4*)(uL + i * P + k0 + 4);
        const float ci = colL[i];
        const float4 va = *(const float4*)(vL + j * P + k0);   // stride-1
        const float4 vb = *(const float4*)(vL + j * P + k0 + 4);
        const float sw = (ci == colL[j]) ? 1.0f : 0.0f;
        const v2f swp = {sw, sw};

        const float uu[8] = {ua.x, ua.y, ua.z, ua.w, ub.x, ub.y, ub.z, ub.w};
        const float vv[8] = {va.x, va.y, va.z, va.w, vb.x, vb.y, vb.z, vb.w};

        union { unsigned w[4]; short8 s; } B;
#pragma unroll
        for (int w = 0; w < 4; ++w) {
            v2f a = {uu[2 * w] + vv[2 * w], uu[2 * w + 1] + vv[2 * w + 1]};
            a = a + swp * w14p[w];
            const v2f h = gelu2(a);
            B.w[w] = cvt_pk_bf16(h.x, h.y);
        }

        f32x4 acc2 = {0.f, 0.f, 0.f, 0.f};
        acc2 = __builtin_amdgcn_mfma_f32_16x16x32_bf16(A.s, B.s, acc2, 0, 0, 0);

        // D: col = e16 (j), row = kq*4+q (e); rows 0..7 valid
        if (kq < 2 && j < SEQ) {
            float* o = out + obb + (size_t)(kq * 4) * NPB + (size_t)i * SEQ + j;
#pragma unroll
            for (int q = 0; q < 4; ++q)
                o[(size_t)q * NPB] = acc2[q] + b2v[q];
        }
    }
}

extern "C" void kernel_launch(void* const* d_in, const int* in_sizes, int n_in,
                              void* d_out, int out_size, void* d_ws, size_t ws_size,
                              hipStream_t stream) {
    const float* x       = (const float*)d_in[0];
    const float* piece_w = (const float*)d_in[1];
    const float* piece_b = (const float*)d_in[2];
    const float* color_w = (const float*)d_in[3];
    const float* color_b = (const float*)d_in[4];
    const float* mlp1_w  = (const float*)d_in[5];
    const float* mlp1_b  = (const float*)d_in[6];
    const float* mlp2_w  = (const float*)d_in[7];
    const float* mlp2_b  = (const float*)d_in[8];
    float* out = (float*)d_out;

    hipLaunchKernelGGL(fused_bias, dim3(BATCHN), dim3(512), 0, stream,
                       x, piece_w, piece_b, color_w, color_b,
                       mlp1_w, mlp1_b, mlp2_w, mlp2_b, out);
}

// Round 15
// 81.355 us; speedup vs baseline: 4.6841x; 1.0943x over previous
//
#include <hip/hip_runtime.h>

#define SEQ 79
#define DM 1024
#define BATCHN 512
#define NPB (SEQ * SEQ)             // 6241
#define P 36                        // k-pitch in floats (16B-aligned, odd/32 banks)
#define NST 395                     // 79 i * 5 j-subtiles of 16
#define NWAVES 4                    // 256-thread block

typedef float v2f   __attribute__((ext_vector_type(2)));
typedef float f32x4 __attribute__((ext_vector_type(4)));
typedef short short8 __attribute__((ext_vector_type(8)));

__device__ __forceinline__ unsigned cvt_pk_bf16(float lo, float hi) {
    unsigned r;
    asm("v_cvt_pk_bf16_f32 %0, %1, %2" : "=v"(r) : "v"(lo), "v"(hi));
    return r;
}

__device__ __forceinline__ v2f gelu2(v2f a) {
    // gelu(a) = a - a / (exp2(c1*a + c2*a^3) + 1)
    const v2f C1 = {2.3022585093f, 2.3022585093f};
    const v2f C2 = {0.1029450750f, 0.1029450750f};
    v2f tt = a * (a * a * C2 + C1);
    v2f e;
    e.x = __builtin_amdgcn_exp2f(tt.x);
    e.y = __builtin_amdgcn_exp2f(tt.y);
    v2f ep = e + (v2f){1.f, 1.f};
    v2f r;
    r.x = __builtin_amdgcn_rcpf(ep.x);
    r.y = __builtin_amdgcn_rcpf(ep.y);
    return a - a * r;
}

// R8 base (proven passing, 82.4us) + dual-subtile ILP in phase B.
// __launch_bounds__(256,2) is the only clean codegen (88 VGPR / 96 SGPR):
//   (1024,8)->32 VGPR spill; (512,4)->64 VGPR spill; (512,2)-> SGPR 32 collapse.
// R13/R14's per-i pipelined restructure NaN'd for reasons never identified ->
// reverted to the flat st loop with loads inside the iteration (R8 semantics).
// This round: each wave runs TWO independent subtiles per iteration
// (st = 2wv + 8m and st+1) as straight-line code; the compiler interleaves
// them so one subtile's LDS latency hides under the other's VALU work.
// Body 1 is always fully defined (stc = min(st+1, NST-1)); only its STORE is
// guarded. No loop-carried registers, no prefetch rotation.
__global__ __launch_bounds__(256, 2) void fused_bias(
    const float* __restrict__ x,
    const float* __restrict__ piece_w, const float* __restrict__ piece_b,
    const float* __restrict__ color_w, const float* __restrict__ color_b,
    const float* __restrict__ mlp1_w,  const float* __restrict__ mlp1_b,
    const float* __restrict__ mlp2_w,  const float* __restrict__ mlp2_b,
    float* __restrict__ out)
{
    __shared__ float uL[80 * P];     // 11,520 B
    __shared__ float vL[80 * P];     // 11,520 B
    __shared__ float colL[80];       // row 79 never written (R8-proven: only
                                     // feeds MFMA col 15, store-guarded)
    const int tid  = threadIdx.x;
    const int lane = tid & 63;
    const int wv   = tid >> 6;       // wave id 0..3
    const int b    = blockIdx.x;
    const int k    = lane & 31;
    const bool is_u = (lane < 32);

    // ---- phase-A per-lane projection weights: c = q*256 + lane*4 + t
    float wp[4][4][7];
#pragma unroll
    for (int q = 0; q < 4; ++q)
#pragma unroll
        for (int t = 0; t < 4; ++t) {
            const int c = q * 256 + lane * 4 + t;
#pragma unroll
            for (int e = 0; e < 6; ++e) wp[q][t][e] = piece_w[c * 6 + e];
            wp[q][t][6] = color_w[c];
        }

    float wsp0 = mlp1_w[0 * 32 + k];
    float wsp1 = mlp1_w[1 * 32 + k];
    if (!is_u) { wsp0 = -wsp0; wsp1 = -wsp1; }
    const float bias1 = is_u ? mlp1_b[k] : 0.0f;
    float wc[6];
#pragma unroll
    for (int c = 0; c < 6; ++c)
        wc[c] = mlp1_w[((is_u ? 2 : 8) + c) * 32 + k];
    float pb[6];
#pragma unroll
    for (int e = 0; e < 6; ++e) pb[e] = piece_b[e];
    const float cb = color_b[0];

    // ---- phase-B lane constants
    const int e16 = lane & 15;          // j-in-subtile / W2 output index
    const int kq  = lane >> 4;          // k-quarter
    const int k0  = kq * 8;

    union { unsigned w[4]; short8 s; } A;   // A-frag = W2^T (rows 8..15 zero)
#pragma unroll
    for (int w = 0; w < 4; ++w) {
        const float lo = (e16 < 8) ? mlp2_w[(k0 + 2 * w) * 8 + e16] : 0.0f;
        const float hi = (e16 < 8) ? mlp2_w[(k0 + 2 * w + 1) * 8 + e16] : 0.0f;
        A.w[w] = cvt_pk_bf16(lo, hi);
    }
    v2f w14p[4];
#pragma unroll
    for (int w = 0; w < 4; ++w)
        w14p[w] = (v2f){mlp1_w[14 * 32 + k0 + 2 * w], mlp1_w[14 * 32 + k0 + 2 * w + 1]};
    float b2v[4];
#pragma unroll
    for (int q = 0; q < 4; ++q)
        b2v[q] = (kq < 2) ? mlp2_b[kq * 4 + q] : 0.0f;

    // ---------------- Phase A: 79 token rows -> LDS ----------------
    const float* xb = x + (size_t)b * SEQ * DM;
    for (int n = wv; n < SEQ; n += NWAVES) {
        const float4* xr = (const float4*)(xb + (size_t)n * DM);
        float4 xv[4];
#pragma unroll
        for (int q = 0; q < 4; ++q) xv[q] = xr[q * 64 + lane];

        float acc[7] = {0.f, 0.f, 0.f, 0.f, 0.f, 0.f, 0.f};
#pragma unroll
        for (int q = 0; q < 4; ++q) {
            const float xs[4] = {xv[q].x, xv[q].y, xv[q].z, xv[q].w};
#pragma unroll
            for (int t = 0; t < 4; ++t)
#pragma unroll
                for (int e = 0; e < 7; ++e)
                    acc[e] = fmaf(xs[t], wp[q][t][e], acc[e]);
        }

#pragma unroll
        for (int e = 0; e < 7; ++e) {
#pragma unroll
            for (int m = 32; m >= 1; m >>= 1)
                acc[e] += __shfl_xor(acc[e], m, 64);
        }

        float p[6];
#pragma unroll
        for (int e = 0; e < 6; ++e) p[e] = acc[e] + pb[e];

        const float fx = (n < 64) ? (float)(n >> 3) : 0.0f;
        const float fy = (n < 64) ? (float)(n & 7) : 0.0f;

        float val = bias1;
        val = fmaf(fx, wsp0, val);
        val = fmaf(fy, wsp1, val);
#pragma unroll
        for (int c = 0; c < 6; ++c) val = fmaf(p[c], wc[c], val);

        float* dst = is_u ? uL : vL;
        dst[n * P + k] = val;
        if (lane == 0) colL[n] = acc[6] + cb;
    }

    __syncthreads();

    // -------- Phase B: two independent 16-pair subtiles per iteration -------
    const size_t obb = (size_t)b * (8 * NPB);
    for (int st = 2 * wv; st < NST; st += 2 * NWAVES) {
        const bool has1 = (st + 1 < NST);
        const int stc = has1 ? st + 1 : st;   // clamped: body1 always defined

        // ---- subtile 0 indices/loads
        const int i0  = st / 5;
        const int jt0 = st - 5 * i0;
        const int j0  = jt0 * 16 + e16;
        const float4 ua0 = *(const float4*)(uL + i0 * P + k0);
        const float4 ub0 = *(const float4*)(uL + i0 * P + k0 + 4);
        const float4 va0 = *(const float4*)(vL + j0 * P + k0);
        const float4 vb0 = *(const float4*)(vL + j0 * P + k0 + 4);
        const float sw0 = (colL[i0] == colL[j0]) ? 1.0f : 0.0f;

        // ---- subtile 1 indices/loads (clamped -> defined; store guarded)
        const int i1  = stc / 5;
        const int jt1 = stc - 5 * i1;
        const int j1  = jt1 * 16 + e16;
        const float4 ua1 = *(const float4*)(uL + i1 * P + k0);
        const float4 ub1 = *(const float4*)(uL + i1 * P + k0 + 4);
        const float4 va1 = *(const float4*)(vL + j1 * P + k0);
        const float4 vb1 = *(const float4*)(vL + j1 * P + k0 + 4);
        const float sw1 = (colL[i1] == colL[j1]) ? 1.0f : 0.0f;

        // ---- compute 0
        const float uu0[8] = {ua0.x, ua0.y, ua0.z, ua0.w, ub0.x, ub0.y, ub0.z, ub0.w};
        const float vv0[8] = {va0.x, va0.y, va0.z, va0.w, vb0.x, vb0.y, vb0.z, vb0.w};
        const v2f swp0 = {sw0, sw0};
        union { unsigned w[4]; short8 s; } B0;
#pragma unroll
        for (int w = 0; w < 4; ++w) {
            v2f a = {uu0[2 * w] + vv0[2 * w], uu0[2 * w + 1] + vv0[2 * w + 1]};
            a = a + swp0 * w14p[w];
            const v2f h = gelu2(a);
            B0.w[w] = cvt_pk_bf16(h.x, h.y);
        }

        // ---- compute 1
        const float uu1[8] = {ua1.x, ua1.y, ua1.z, ua1.w, ub1.x, ub1.y, ub1.z, ub1.w};
        const float vv1[8] = {va1.x, va1.y, va1.z, va1.w, vb1.x, vb1.y, vb1.z, vb1.w};
        const v2f swp1 = {sw1, sw1};
        union { unsigned w[4]; short8 s; } B1;
#pragma unroll
        for (int w = 0; w < 4; ++w) {
            v2f a = {uu1[2 * w] + vv1[2 * w], uu1[2 * w + 1] + vv1[2 * w + 1]};
            a = a + swp1 * w14p[w];
            const v2f h = gelu2(a);
            B1.w[w] = cvt_pk_bf16(h.x, h.y);
        }

        f32x4 acc0 = {0.f, 0.f, 0.f, 0.f};
        acc0 = __builtin_amdgcn_mfma_f32_16x16x32_bf16(A.s, B0.s, acc0, 0, 0, 0);
        f32x4 acc1 = {0.f, 0.f, 0.f, 0.f};
        acc1 = __builtin_amdgcn_mfma_f32_16x16x32_bf16(A.s, B1.s, acc1, 0, 0, 0);

        // ---- stores (D: col = e16, row = kq*4+q; rows 0..7 valid)
        if (kq < 2 && j0 < SEQ) {
            float* o = out + obb + (size_t)(kq * 4) * NPB + (size_t)i0 * SEQ + j0;
#pragma unroll
            for (int q = 0; q < 4; ++q)
                o[(size_t)q * NPB] = acc0[q] + b2v[q];
        }
        if (has1 && kq < 2 && j1 < SEQ) {
            float* o = out + obb + (size_t)(kq * 4) * NPB + (size_t)i1 * SEQ + j1;
#pragma unroll
            for (int q = 0; q < 4; ++q)
                o[(size_t)q * NPB] = acc1[q] + b2v[q];
        }
    }
}

extern "C" void kernel_launch(void* const* d_in, const int* in_sizes, int n_in,
                              void* d_out, int out_size, void* d_ws, size_t ws_size,
                              hipStream_t stream) {
    const float* x       = (const float*)d_in[0];
    const float* piece_w = (const float*)d_in[1];
    const float* piece_b = (const float*)d_in[2];
    const float* color_w = (const float*)d_in[3];
    const float* color_b = (const float*)d_in[4];
    const float* mlp1_w  = (const float*)d_in[5];
    const float* mlp1_b  = (const float*)d_in[6];
    const float* mlp2_w  = (const float*)d_in[7];
    const float* mlp2_b  = (const float*)d_in[8];
    float* out = (float*)d_out;

    hipLaunchKernelGGL(fused_bias, dim3(BATCHN), dim3(256), 0, stream,
                       x, piece_w, piece_b, color_w, color_b,
                       mlp1_w, mlp1_b, mlp2_w, mlp2_b, out);
}

// Round 16
// 72.251 us; speedup vs baseline: 5.2744x; 1.1260x over previous
//
#include <hip/hip_runtime.h>

#define SEQ 79
#define DM 1024
#define BATCHN 512
#define NPB (SEQ * SEQ)             // 6241
#define P 36                        // k-pitch in floats (16B-aligned, odd/32 banks)
#define NWAVES 4                    // 256-thread block

typedef float v2f   __attribute__((ext_vector_type(2)));
typedef float f32x4 __attribute__((ext_vector_type(4)));
typedef short short8 __attribute__((ext_vector_type(8)));

__device__ __forceinline__ unsigned cvt_pk_bf16(float lo, float hi) {
    unsigned r;
    asm("v_cvt_pk_bf16_f32 %0, %1, %2" : "=v"(r) : "v"(lo), "v"(hi));
    return r;
}

// DPP-based add of a row-of-16 permutation: runs on the VALU pipe, NOT the
// LDS pipe (unlike __shfl_xor -> ds_bpermute). ctrl: 0xB1 = quad_perm
// [1,0,3,2] (xor1), 0x4E = quad_perm [2,3,0,1] (xor2), 0x124 = row_ror:4,
// 0x128 = row_ror:8. After these 4 adds every lane of each 16-row holds the
// 16-lane sum.
template <int CTRL>
__device__ __forceinline__ float dpp_add(float v) {
    int t = __builtin_amdgcn_update_dpp(0, __builtin_bit_cast(int, v),
                                        CTRL, 0xf, 0xf, false);
    return v + __builtin_bit_cast(float, t);
}

__device__ __forceinline__ v2f gelu2(v2f a) {
    // gelu(a) = a - a / (exp2(c1*a + c2*a^3) + 1)
    const v2f C1 = {2.3022585093f, 2.3022585093f};
    const v2f C2 = {0.1029450750f, 0.1029450750f};
    v2f tt = a * (a * a * C2 + C1);
    v2f e;
    e.x = __builtin_amdgcn_exp2f(tt.x);
    e.y = __builtin_amdgcn_exp2f(tt.y);
    v2f ep = e + (v2f){1.f, 1.f};
    v2f r;
    r.x = __builtin_amdgcn_rcpf(ep.x);
    r.y = __builtin_amdgcn_rcpf(ep.y);
    return a - a * r;
}

// R15 base (passing, 81.4us) with the LDS PIPE (measured ~42us/CU of
// serialized ds traffic) attacked on both phases:
//  - phase A reduce: masks 1,2,4,8 via DPP (VALU pipe), only 16/32 via shfl
//    -> 42 ds ops/row -> 14.
//  - phase B: i-outer loop, u/col[i] hoisted once per 5 subtiles
//    -> 4 b128/subtile -> 2.4. Loads stay direct (R15 style), no rotation,
//    no loop-carried registers; store pointers formed inside the guard.
// __launch_bounds__(256,2) is the only clean codegen (88 VGPR / 96 SGPR):
//   (1024,8)->32 VGPR spill; (512,4)->64 VGPR spill; (512,2)->SGPR collapse.
__global__ __launch_bounds__(256, 2) void fused_bias(
    const float* __restrict__ x,
    const float* __restrict__ piece_w, const float* __restrict__ piece_b,
    const float* __restrict__ color_w, const float* __restrict__ color_b,
    const float* __restrict__ mlp1_w,  const float* __restrict__ mlp1_b,
    const float* __restrict__ mlp2_w,  const float* __restrict__ mlp2_b,
    float* __restrict__ out)
{
    __shared__ float uL[80 * P];     // 11,520 B
    __shared__ float vL[80 * P];     // 11,520 B
    __shared__ float colL[80];

    const int tid  = threadIdx.x;
    const int lane = tid & 63;
    const int wv   = tid >> 6;       // wave id 0..3
    const int b    = blockIdx.x;
    const int k    = lane & 31;
    const bool is_u = (lane < 32);

    // ---- phase-A per-lane projection weights: c = q*256 + lane*4 + t
    float wp[4][4][7];
#pragma unroll
    for (int q = 0; q < 4; ++q)
#pragma unroll
        for (int t = 0; t < 4; ++t) {
            const int c = q * 256 + lane * 4 + t;
#pragma unroll
            for (int e = 0; e < 6; ++e) wp[q][t][e] = piece_w[c * 6 + e];
            wp[q][t][6] = color_w[c];
        }

    float wsp0 = mlp1_w[0 * 32 + k];
    float wsp1 = mlp1_w[1 * 32 + k];
    if (!is_u) { wsp0 = -wsp0; wsp1 = -wsp1; }
    const float bias1 = is_u ? mlp1_b[k] : 0.0f;
    float wc[6];
#pragma unroll
    for (int c = 0; c < 6; ++c)
        wc[c] = mlp1_w[((is_u ? 2 : 8) + c) * 32 + k];
    float pb[6];
#pragma unroll
    for (int e = 0; e < 6; ++e) pb[e] = piece_b[e];
    const float cb = color_b[0];

    // ---- phase-B lane constants
    const int e16 = lane & 15;          // j-in-subtile / W2 output index
    const int kq  = lane >> 4;          // k-quarter
    const int k0  = kq * 8;

    union { unsigned w[4]; short8 s; } A;   // A-frag = W2^T (rows 8..15 zero)
#pragma unroll
    for (int w = 0; w < 4; ++w) {
        const float lo = (e16 < 8) ? mlp2_w[(k0 + 2 * w) * 8 + e16] : 0.0f;
        const float hi = (e16 < 8) ? mlp2_w[(k0 + 2 * w + 1) * 8 + e16] : 0.0f;
        A.w[w] = cvt_pk_bf16(lo, hi);
    }
    v2f w14p[4];
#pragma unroll
    for (int w = 0; w < 4; ++w)
        w14p[w] = (v2f){mlp1_w[14 * 32 + k0 + 2 * w], mlp1_w[14 * 32 + k0 + 2 * w + 1]};
    float b2v[4];
#pragma unroll
    for (int q = 0; q < 4; ++q)
        b2v[q] = (kq < 2) ? mlp2_b[kq * 4 + q] : 0.0f;

    // defined padding for row 79 (j==79 reads feed MFMA col 15, store-guarded)
    if (wv == 0) {
        if (lane < P) vL[79 * P + lane] = 0.0f;
        if (lane == 0) colL[79] = 0.0f;
    }

    // ---------------- Phase A: 79 token rows -> LDS ----------------
    const float* xb = x + (size_t)b * SEQ * DM;
    for (int n = wv; n < SEQ; n += NWAVES) {
        const float4* xr = (const float4*)(xb + (size_t)n * DM);
        float4 xv[4];
#pragma unroll
        for (int q = 0; q < 4; ++q) xv[q] = xr[q * 64 + lane];

        float acc[7] = {0.f, 0.f, 0.f, 0.f, 0.f, 0.f, 0.f};
#pragma unroll
        for (int q = 0; q < 4; ++q) {
            const float xs[4] = {xv[q].x, xv[q].y, xv[q].z, xv[q].w};
#pragma unroll
            for (int t = 0; t < 4; ++t)
#pragma unroll
                for (int e = 0; e < 7; ++e)
                    acc[e] = fmaf(xs[t], wp[q][t][e], acc[e]);
        }

        // 64-lane sum: 4 DPP steps (VALU pipe) + 2 shfl (LDS pipe)
#pragma unroll
        for (int e = 0; e < 7; ++e) {
            acc[e] = dpp_add<0xB1>(acc[e]);    // xor1 (quad_perm [1,0,3,2])
            acc[e] = dpp_add<0x4E>(acc[e]);    // xor2 (quad_perm [2,3,0,1])
            acc[e] = dpp_add<0x124>(acc[e]);   // row_ror:4
            acc[e] = dpp_add<0x128>(acc[e]);   // row_ror:8 -> 16-lane sums
            acc[e] += __shfl_xor(acc[e], 16, 64);
            acc[e] += __shfl_xor(acc[e], 32, 64);
        }

        float p[6];
#pragma unroll
        for (int e = 0; e < 6; ++e) p[e] = acc[e] + pb[e];

        const float fx = (n < 64) ? (float)(n >> 3) : 0.0f;
        const float fy = (n < 64) ? (float)(n & 7) : 0.0f;

        float val = bias1;
        val = fmaf(fx, wsp0, val);
        val = fmaf(fy, wsp1, val);
#pragma unroll
        for (int c = 0; c < 6; ++c) val = fmaf(p[c], wc[c], val);

        float* dst = is_u ? uL : vL;
        dst[n * P + k] = val;
        if (lane == 0) colL[n] = acc[6] + cb;
    }

    __syncthreads();

    // ------- Phase B: i-outer (u/col hoisted), 5 j-subtiles per i -------
    const size_t obb = (size_t)b * (8 * NPB);
    for (int i = wv; i < SEQ; i += NWAVES) {
        const float4 ua = *(const float4*)(uL + i * P + k0);   // per-i, 1x
        const float4 ub = *(const float4*)(uL + i * P + k0 + 4);
        const float ci = colL[i];
        const float uu[8] = {ua.x, ua.y, ua.z, ua.w, ub.x, ub.y, ub.z, ub.w};

#pragma unroll
        for (int jt = 0; jt < 5; ++jt) {
            const int j = jt * 16 + e16;       // 79 possible on last subtile
            const float4 va = *(const float4*)(vL + j * P + k0);
            const float4 vb = *(const float4*)(vL + j * P + k0 + 4);
            const float sw = (ci == colL[j]) ? 1.0f : 0.0f;
            const v2f swp = {sw, sw};
            const float vv[8] = {va.x, va.y, va.z, va.w, vb.x, vb.y, vb.z, vb.w};

            union { unsigned w[4]; short8 s; } B;
#pragma unroll
            for (int w = 0; w < 4; ++w) {
                v2f a = {uu[2 * w] + vv[2 * w], uu[2 * w + 1] + vv[2 * w + 1]};
                a = a + swp * w14p[w];
                const v2f h = gelu2(a);
                B.w[w] = cvt_pk_bf16(h.x, h.y);
            }

            f32x4 acc2 = {0.f, 0.f, 0.f, 0.f};
            acc2 = __builtin_amdgcn_mfma_f32_16x16x32_bf16(A.s, B.s, acc2, 0, 0, 0);

            // D: col = e16 (j), row = kq*4+q (e); rows 0..7 valid
            if (kq < 2 && j < SEQ) {
                float* o = out + obb + (size_t)(kq * 4) * NPB + (size_t)i * SEQ + j;
#pragma unroll
                for (int q = 0; q < 4; ++q)
                    o[(size_t)q * NPB] = acc2[q] + b2v[q];
            }
        }
    }
}

extern "C" void kernel_launch(void* const* d_in, const int* in_sizes, int n_in,
                              void* d_out, int out_size, void* d_ws, size_t ws_size,
                              hipStream_t stream) {
    const float* x       = (const float*)d_in[0];
    const float* piece_w = (const float*)d_in[1];
    const float* piece_b = (const float*)d_in[2];
    const float* color_w = (const float*)d_in[3];
    const float* color_b = (const float*)d_in[4];
    const float* mlp1_w  = (const float*)d_in[5];
    const float* mlp1_b  = (const float*)d_in[6];
    const float* mlp2_w  = (const float*)d_in[7];
    const float* mlp2_b  = (const float*)d_in[8];
    float* out = (float*)d_out;

    hipLaunchKernelGGL(fused_bias, dim3(BATCHN), dim3(256), 0, stream,
                       x, piece_w, piece_b, color_w, color_b,
                       mlp1_w, mlp1_b, mlp2_w, mlp2_b, out);
}

// Round 17
// 69.789 us; speedup vs baseline: 5.4604x; 1.0353x over previous
//
#include <hip/hip_runtime.h>

#define SEQ 79
#define DM 1024
#define BATCHN 512
#define NPB (SEQ * SEQ)             // 6241
#define P 36                        // k-pitch in floats (16B-aligned, odd/32 banks)
#define NWAVES 4                    // 256-thread block

typedef float v2f   __attribute__((ext_vector_type(2)));
typedef float f32x4 __attribute__((ext_vector_type(4)));
typedef short short8 __attribute__((ext_vector_type(8)));

__device__ __forceinline__ unsigned cvt_pk_bf16(float lo, float hi) {
    unsigned r;
    asm("v_cvt_pk_bf16_f32 %0, %1, %2" : "=v"(r) : "v"(lo), "v"(hi));
    return r;
}

// DPP lane-shuffle add on the VALU pipe (not LDS): 0xB1=xor1, 0x4E=xor2,
// 0x124=row_ror:4, 0x128=row_ror:8 -> 16-lane sums after 4 steps.
template <int CTRL>
__device__ __forceinline__ float dpp_add(float v) {
    int t = __builtin_amdgcn_update_dpp(0, __builtin_bit_cast(int, v),
                                        CTRL, 0xf, 0xf, false);
    return v + __builtin_bit_cast(float, t);
}

__device__ __forceinline__ v2f gelu2(v2f a) {
    // gelu(a) = a - a / (exp2(c1*a + c2*a^3) + 1)
    const v2f C1 = {2.3022585093f, 2.3022585093f};
    const v2f C2 = {0.1029450750f, 0.1029450750f};
    v2f tt = a * (a * a * C2 + C1);
    v2f e;
    e.x = __builtin_amdgcn_exp2f(tt.x);
    e.y = __builtin_amdgcn_exp2f(tt.y);
    v2f ep = e + (v2f){1.f, 1.f};
    v2f r;
    r.x = __builtin_amdgcn_rcpf(ep.x);
    r.y = __builtin_amdgcn_rcpf(ep.y);
    return a - a * r;
}

// R16 base (passing, 72.3us; LDS-pipe diagnosis CONFIRMED: DPP+u-hoist -9us).
// This round: phase-B v/col[j] are i-INVARIANT per lane -> hoisted to
// registers ONCE per wave after the barrier (40+5 VGPR). Inner loop LDS =
// only the per-i u-load. Plain __launch_bounds__(256): VGPR cap lifted
// (occupancy is grid-limited at 2 blocks/CU; VGPR<=256 costs nothing).
// TRIPWIRE: FETCH >> 81MB = spill -> revert.
__global__ __launch_bounds__(256) void fused_bias(
    const float* __restrict__ x,
    const float* __restrict__ piece_w, const float* __restrict__ piece_b,
    const float* __restrict__ color_w, const float* __restrict__ color_b,
    const float* __restrict__ mlp1_w,  const float* __restrict__ mlp1_b,
    const float* __restrict__ mlp2_w,  const float* __restrict__ mlp2_b,
    float* __restrict__ out)
{
    __shared__ float uL[80 * P];     // 11,520 B
    __shared__ float vL[80 * P];     // 11,520 B
    __shared__ float colL[80];

    const int tid  = threadIdx.x;
    const int lane = tid & 63;
    const int wv   = tid >> 6;       // wave id 0..3
    const int b    = blockIdx.x;
    const int k    = lane & 31;
    const bool is_u = (lane < 32);

    // ---- phase-A per-lane projection weights: c = q*256 + lane*4 + t
    float wp[4][4][7];
#pragma unroll
    for (int q = 0; q < 4; ++q)
#pragma unroll
        for (int t = 0; t < 4; ++t) {
            const int c = q * 256 + lane * 4 + t;
#pragma unroll
            for (int e = 0; e < 6; ++e) wp[q][t][e] = piece_w[c * 6 + e];
            wp[q][t][6] = color_w[c];
        }

    float wsp0 = mlp1_w[0 * 32 + k];
    float wsp1 = mlp1_w[1 * 32 + k];
    if (!is_u) { wsp0 = -wsp0; wsp1 = -wsp1; }
    const float bias1 = is_u ? mlp1_b[k] : 0.0f;
    float wc[6];
#pragma unroll
    for (int c = 0; c < 6; ++c)
        wc[c] = mlp1_w[((is_u ? 2 : 8) + c) * 32 + k];
    float pb[6];
#pragma unroll
    for (int e = 0; e < 6; ++e) pb[e] = piece_b[e];
    const float cb = color_b[0];

    // ---- phase-B lane constants
    const int e16 = lane & 15;          // j-in-subtile / W2 output index
    const int kq  = lane >> 4;          // k-quarter
    const int k0  = kq * 8;

    union { unsigned w[4]; short8 s; } A;   // A-frag = W2^T (rows 8..15 zero)
#pragma unroll
    for (int w = 0; w < 4; ++w) {
        const float lo = (e16 < 8) ? mlp2_w[(k0 + 2 * w) * 8 + e16] : 0.0f;
        const float hi = (e16 < 8) ? mlp2_w[(k0 + 2 * w + 1) * 8 + e16] : 0.0f;
        A.w[w] = cvt_pk_bf16(lo, hi);
    }
    v2f w14p[4];
#pragma unroll
    for (int w = 0; w < 4; ++w)
        w14p[w] = (v2f){mlp1_w[14 * 32 + k0 + 2 * w], mlp1_w[14 * 32 + k0 + 2 * w + 1]};
    float b2v[4];
#pragma unroll
    for (int q = 0; q < 4; ++q)
        b2v[q] = (kq < 2) ? mlp2_b[kq * 4 + q] : 0.0f;

    // defined padding for row 79 (j==79 reads feed MFMA col 15, store-guarded)
    if (wv == 0) {
        if (lane < P) vL[79 * P + lane] = 0.0f;
        if (lane == 0) colL[79] = 0.0f;
    }

    // ---------------- Phase A: 79 token rows -> LDS ----------------
    const float* xb = x + (size_t)b * SEQ * DM;
    for (int n = wv; n < SEQ; n += NWAVES) {
        const float4* xr = (const float4*)(xb + (size_t)n * DM);
        float4 xv[4];
#pragma unroll
        for (int q = 0; q < 4; ++q) xv[q] = xr[q * 64 + lane];

        float acc[7] = {0.f, 0.f, 0.f, 0.f, 0.f, 0.f, 0.f};
#pragma unroll
        for (int q = 0; q < 4; ++q) {
            const float xs[4] = {xv[q].x, xv[q].y, xv[q].z, xv[q].w};
#pragma unroll
            for (int t = 0; t < 4; ++t)
#pragma unroll
                for (int e = 0; e < 7; ++e)
                    acc[e] = fmaf(xs[t], wp[q][t][e], acc[e]);
        }

        // 64-lane sum: 4 DPP steps (VALU pipe) + 2 shfl (LDS pipe)
#pragma unroll
        for (int e = 0; e < 7; ++e) {
            acc[e] = dpp_add<0xB1>(acc[e]);
            acc[e] = dpp_add<0x4E>(acc[e]);
            acc[e] = dpp_add<0x124>(acc[e]);
            acc[e] = dpp_add<0x128>(acc[e]);
            acc[e] += __shfl_xor(acc[e], 16, 64);
            acc[e] += __shfl_xor(acc[e], 32, 64);
        }

        float p[6];
#pragma unroll
        for (int e = 0; e < 6; ++e) p[e] = acc[e] + pb[e];

        const float fx = (n < 64) ? (float)(n >> 3) : 0.0f;
        const float fy = (n < 64) ? (float)(n & 7) : 0.0f;

        float val = bias1;
        val = fmaf(fx, wsp0, val);
        val = fmaf(fy, wsp1, val);
#pragma unroll
        for (int c = 0; c < 6; ++c) val = fmaf(p[c], wc[c], val);

        float* dst = is_u ? uL : vL;
        dst[n * P + k] = val;
        if (lane == 0) colL[n] = acc[6] + cb;
    }

    __syncthreads();

    // ---- Phase B prologue: hoist this lane's i-invariant v/col[j] into regs
    float vv[5][8];
    float cjv[5];
#pragma unroll
    for (int jt = 0; jt < 5; ++jt) {
        const int j = jt * 16 + e16;           // j==79 reads defined padding
        const float4 va = *(const float4*)(vL + j * P + k0);
        const float4 vb = *(const float4*)(vL + j * P + k0 + 4);
        vv[jt][0] = va.x; vv[jt][1] = va.y; vv[jt][2] = va.z; vv[jt][3] = va.w;
        vv[jt][4] = vb.x; vv[jt][5] = vb.y; vv[jt][6] = vb.z; vv[jt][7] = vb.w;
        cjv[jt] = colL[j];
    }

    // ------- Phase B: i-outer; inner 5 subtiles fully register-resident -----
    const size_t obb = (size_t)b * (8 * NPB);
    for (int i = wv; i < SEQ; i += NWAVES) {
        const float4 ua = *(const float4*)(uL + i * P + k0);   // per-i LDS
        const float4 ub = *(const float4*)(uL + i * P + k0 + 4);
        const float ci = colL[i];
        const float uu[8] = {ua.x, ua.y, ua.z, ua.w, ub.x, ub.y, ub.z, ub.w};

#pragma unroll
        for (int jt = 0; jt < 5; ++jt) {
            const int j = jt * 16 + e16;
            const float sw = (ci == cjv[jt]) ? 1.0f : 0.0f;
            const v2f swp = {sw, sw};

            union { unsigned w[4]; short8 s; } B;
#pragma unroll
            for (int w = 0; w < 4; ++w) {
                v2f a = {uu[2 * w] + vv[jt][2 * w], uu[2 * w + 1] + vv[jt][2 * w + 1]};
                a = a + swp * w14p[w];
                const v2f h = gelu2(a);
                B.w[w] = cvt_pk_bf16(h.x, h.y);
            }

            f32x4 acc2 = {0.f, 0.f, 0.f, 0.f};
            acc2 = __builtin_amdgcn_mfma_f32_16x16x32_bf16(A.s, B.s, acc2, 0, 0, 0);

            // D: col = e16 (j), row = kq*4+q (e); rows 0..7 valid
            if (kq < 2 && j < SEQ) {
                float* o = out + obb + (size_t)(kq * 4) * NPB + (size_t)i * SEQ + j;
#pragma unroll
                for (int q = 0; q < 4; ++q)
                    o[(size_t)q * NPB] = acc2[q] + b2v[q];
            }
        }
    }
}

extern "C" void kernel_launch(void* const* d_in, const int* in_sizes, int n_in,
                              void* d_out, int out_size, void* d_ws, size_t ws_size,
                              hipStream_t stream) {
    const float* x       = (const float*)d_in[0];
    const float* piece_w = (const float*)d_in[1];
    const float* piece_b = (const float*)d_in[2];
    const float* color_w = (const float*)d_in[3];
    const float* color_b = (const float*)d_in[4];
    const float* mlp1_w  = (const float*)d_in[5];
    const float* mlp1_b  = (const float*)d_in[6];
    const float* mlp2_w  = (const float*)d_in[7];
    const float* mlp2_b  = (const float*)d_in[8];
    float* out = (float*)d_out;

    hipLaunchKernelGGL(fused_bias, dim3(BATCHN), dim3(256), 0, stream,
                       x, piece_w, piece_b, color_w, color_b,
                       mlp1_w, mlp1_b, mlp2_w, mlp2_b, out);
}